// Round 4
// baseline (15.598 us; speedup 1.0000x reference)
//
#include <hip/hip_runtime.h>
#include <float.h>

#define BB 256
#define VV 10475
#define RR 75
#define KK 5
#define RKN (RR * KK)     // 375 gathered points per array
#define NOUT (RR * RR)    // 5625 entries per batch
#define TI 3
#define TJ 3
#define NTI (RR / TI)     // 25
#define NTJ (RR / TJ)     // 25
#define NTILE (NTI * NTJ) // 625 active compute threads
#define TPB 768           // 12 waves: 750 gather threads, 625 compute threads

__global__ __launch_bounds__(TPB) void ContactMap_47691316854895_kernel(
    const float* __restrict__ v1,
    const float* __restrict__ v2,
    const int* __restrict__ rid,
    float* __restrict__ out)
{
    __shared__ float4 g1s[RKN];   // 6 KB
    __shared__ float4 g2s[RKN];   // 6 KB
    __shared__ float  outs[NOUT]; // 22.5 KB

    const int b = blockIdx.x;
    const int tid = threadIdx.x;

    // Distributed gather: threads 0-374 handle v1, 375-749 handle v2.
    // 3 dependent scattered loads per thread (was 6).
    if (tid < RKN) {
        const int idx = rid[tid];
        const float* p = v1 + ((size_t)b * VV + idx) * 3;
        g1s[tid] = make_float4(p[0], p[1], p[2], 0.0f);
    } else if (tid < 2 * RKN) {
        const int t = tid - RKN;
        const int idx = rid[t];
        const float* p = v2 + ((size_t)b * VV + idx) * 3;
        g2s[t] = make_float4(p[0], p[1], p[2], 0.0f);
    }
    __syncthreads();

    if (tid < NTILE) {
        const int i0 = (tid / NTJ) * TI;
        const int j0 = (tid % NTJ) * TJ;

        // Hoist the 3 a-residues (15 points) into registers.
        float ax[TI][KK], ay[TI][KK], az[TI][KK];
#pragma unroll
        for (int ii = 0; ii < TI; ++ii) {
#pragma unroll
            for (int p = 0; p < KK; ++p) {
                const float4 a = g1s[(i0 + ii) * KK + p];
                ax[ii][p] = a.x; ay[ii][p] = a.y; az[ii][p] = a.z;
            }
        }

#pragma unroll
        for (int jj = 0; jj < TJ; ++jj) {
            float bx[KK], by[KK], bz[KK];
#pragma unroll
            for (int q = 0; q < KK; ++q) {
                const float4 v = g2s[(j0 + jj) * KK + q];
                bx[q] = v.x; by[q] = v.y; bz[q] = v.z;
            }
#pragma unroll
            for (int ii = 0; ii < TI; ++ii) {
                float best = FLT_MAX;
#pragma unroll
                for (int p = 0; p < KK; ++p) {
#pragma unroll
                    for (int q = 0; q < KK; ++q) {
                        const float dx = ax[ii][p] - bx[q];
                        const float dy = ay[ii][p] - by[q];
                        const float dz = az[ii][p] - bz[q];
                        const float d2 = dx * dx + dy * dy + dz * dz;
                        best = fminf(best, d2);
                    }
                }
                outs[(i0 + ii) * RR + (j0 + jj)] = best;  // d^2; sqrt in store pass
            }
        }
    }
    __syncthreads();

    // Coalesced store pass with fused sqrt: 64 contiguous floats per wave instr.
    float* outb = out + (size_t)b * NOUT;
    for (int e = tid; e < NOUT; e += TPB) {
        outb[e] = sqrtf(outs[e]);
    }
}

extern "C" void kernel_launch(void* const* d_in, const int* in_sizes, int n_in,
                              void* d_out, int out_size, void* d_ws, size_t ws_size,
                              hipStream_t stream) {
    const float* v1 = (const float*)d_in[0];
    const float* v2 = (const float*)d_in[1];
    const int* rid = (const int*)d_in[2];
    float* out = (float*)d_out;

    ContactMap_47691316854895_kernel<<<dim3(BB), dim3(TPB), 0, stream>>>(v1, v2, rid, out);
}